// Round 1
// baseline (54.412 us; speedup 1.0000x reference)
//
#include <hip/hip_runtime.h>

// SSIM v13: v12 structure (wave-autonomous MFMA conv, no data-LDS, no
// mid-kernel barriers) with BY 256 -> 128. v12's grid was 768 blocks =
// 3 blocks/CU = 37.5% occupancy cap; all pipes idle together (latency-
// bound: MfmaUtil 5%, VALU 31%, HBM 22%). BY=128 doubles the grid to
// 1536 blocks = 6 blocks/CU (75% wave ceiling) at +5.9% halo work.
// Each wave owns a 16-col x BY-row strip; per 16-row chunk:
//   global->reg load -> 5 H-MFMAs -> (shfl-rebuild B-frag) -> 5 V-MFMAs -> SSIM.
// Layout identity: V B-frag rows lg*8+2w{,+1} = uint2 of H D-frag at source
// lane ln+lg_s*16 (lg_s=(w>>1)+(lg&1)*2), tile = chunk t (lg<2) / t+1 (lg>=2).
// Chunk base -8 makes the V weight band == H band -> single weight fragment.
// Per-pixel math bit-identical to v12 (absmax must be exactly 0.0078125).

typedef __attribute__((ext_vector_type(8))) short bf16x8;
typedef __attribute__((ext_vector_type(4))) float f32x4;

constexpr int PAD  = 5;
constexpr int TX   = 64;             // block out-cols (4 waves x 16)
constexpr int BY   = 128;            // block out-rows
constexpr int IMW  = 512;
constexpr int IMH  = 512;
constexpr int NPL  = 48;
constexpr int GX   = IMW / TX;       // 8
constexpr int GYB  = IMH / BY;       // 4
constexpr int NBLK = GX * GYB * NPL; // 1536
constexpr int NTT  = BY / 32;        // main-loop iterations (2 tiles each)
constexpr float C1c = 0.01f * 0.01f;
constexpr float C2c = 0.03f * 0.03f;

union frag {
    bf16x8 f;
    unsigned int u[4];
    uint4 q;
};

// RNE f32->bf16 pair pack (setup kernel only).
__device__ __forceinline__ unsigned int pk_bf16(float lo, float hi) {
    unsigned int a = __float_as_uint(lo);
    unsigned int b = __float_as_uint(hi);
    a += 0x7FFFu + ((a >> 16) & 1u);
    b += 0x7FFFu + ((b >> 16) & 1u);
    return (b & 0xFFFF0000u) | (a >> 16);
}

// Fast pack: round-half-up + byte-perm merge (3 VALU ops per pair).
__device__ __forceinline__ unsigned int pk_rhu(float lo, float hi, unsigned sel) {
    unsigned int a = __float_as_uint(lo) + 0x8000u;
    unsigned int b = __float_as_uint(hi) + 0x8000u;
    unsigned int r;
    asm("v_perm_b32 %0, %1, %2, %3" : "=v"(r) : "v"(b), "v"(a), "s"(sel));
    return r;
}

// Normalized 11-tap Gaussian (sigma=1.5); wt[d] for d in [0,11), else 0.
__device__ __forceinline__ float wsel(int d) {
    float w = 0.f;
    w = (d == 0 || d == 10) ? 0.00102838f : w;
    w = (d == 1 || d == 9)  ? 0.00759876f : w;
    w = (d == 2 || d == 8)  ? 0.03600077f : w;
    w = (d == 3 || d == 7)  ? 0.10936082f : w;
    w = (d == 4 || d == 6)  ? 0.21300553f : w;
    w = (d == 5)            ? 0.26601171f : w;
    return w;
}

// Per-lane shared weight fragment: W[k][n] = wt[k-n-3], k=lg*8+j, n=ln.
__global__ void ssim_weight_setup(unsigned int* __restrict__ wbuf)
{
    const int lane = threadIdx.x & 63;
    const int ln   = lane & 15;
    const int lg   = lane >> 4;
#pragma unroll
    for (int w = 0; w < 4; ++w) {
        const int ka = lg * 8 + 2 * w;
        wbuf[lane * 4 + w] = pk_bf16(wsel(ka - ln - 3), wsel(ka + 1 - ln - 3));
    }
}

__global__ __launch_bounds__(256, 4)
void ssim_mfma(const float* __restrict__ img1, const float* __restrict__ img2,
               const unsigned int* __restrict__ wbuf,
               float* __restrict__ partials)
{
    const int tid  = threadIdx.x;
    const int lane = tid & 63;
    const int wave = tid >> 6;        // 0..3
    const int ln   = lane & 15;
    const int lg   = lane >> 4;       // 0..3
    const int tx0w = blockIdx.x * TX + wave * 16;   // wave's 16 out-cols
    const int y0   = blockIdx.y * BY;
    const float* __restrict__ p1 = img1 + (size_t)blockIdx.z * (IMW * IMH);
    const float* __restrict__ p2 = img2 + (size_t)blockIdx.z * (IMW * IMH);
    const unsigned int sel = 0x07060302u;

    frag whf;
    whf.q = reinterpret_cast<const uint4*>(wbuf)[lane];

    const f32x4 z = {0.f, 0.f, 0.f, 0.f};
    const int cbase = tx0w - 8 + lg * 8;            // lane's first img col
    const int srcA  = ln + ((lg & 1) << 5);         // shfl src, w=0,1
    const int srcB  = srcA + 16;                    // shfl src, w=2,3
    const bool hi   = (lg >= 2);                    // rows 16..31 -> D_cur

    // Load chunk c: 16 h-rows (img rows y0+16c-8 .. +7), 32 cols window.
    auto hload = [&](int c, float* a, float* b) {
        const int irow = y0 + 16 * c - 8 + ln;
        const bool rowok = (unsigned)irow < (unsigned)IMH;
#pragma unroll
        for (int h = 0; h < 2; ++h) {
            const int c4 = cbase + 4 * h;
            float4 va = make_float4(0.f, 0.f, 0.f, 0.f);
            float4 vb = make_float4(0.f, 0.f, 0.f, 0.f);
            if (rowok && ((unsigned)c4 <= (unsigned)(IMW - 4))) {
                va = *reinterpret_cast<const float4*>(p1 + (size_t)irow * IMW + c4);
                vb = *reinterpret_cast<const float4*>(p2 + (size_t)irow * IMW + c4);
            }
            a[4*h+0] = va.x; a[4*h+1] = va.y; a[4*h+2] = va.z; a[4*h+3] = va.w;
            b[4*h+0] = vb.x; b[4*h+1] = vb.y; b[4*h+2] = vb.z; b[4*h+3] = vb.w;
        }
    };

    // H-pass for one chunk: 5 MFMAs -> packed D (uint2 per plane).
    auto hproc = [&](const float* a, const float* b, uint2* D) {
        frag fa, fb, faa, fbb, fab;
#pragma unroll
        for (int w = 0; w < 4; ++w) {
            const float a0 = a[2*w], a1 = a[2*w+1];
            const float b0 = b[2*w], b1 = b[2*w+1];
            fa.u[w]  = pk_rhu(a0,      a1,      sel);
            fb.u[w]  = pk_rhu(b0,      b1,      sel);
            faa.u[w] = pk_rhu(a0 * a0, a1 * a1, sel);
            fbb.u[w] = pk_rhu(b0 * b0, b1 * b1, sel);
            fab.u[w] = pk_rhu(a0 * b0, a1 * b1, sel);
        }
        f32x4 d;
        d = __builtin_amdgcn_mfma_f32_16x16x32_bf16(fa.f,  whf.f, z, 0, 0, 0);
        D[0] = make_uint2(pk_rhu(d[0], d[1], sel), pk_rhu(d[2], d[3], sel));
        d = __builtin_amdgcn_mfma_f32_16x16x32_bf16(fb.f,  whf.f, z, 0, 0, 0);
        D[1] = make_uint2(pk_rhu(d[0], d[1], sel), pk_rhu(d[2], d[3], sel));
        d = __builtin_amdgcn_mfma_f32_16x16x32_bf16(faa.f, whf.f, z, 0, 0, 0);
        D[2] = make_uint2(pk_rhu(d[0], d[1], sel), pk_rhu(d[2], d[3], sel));
        d = __builtin_amdgcn_mfma_f32_16x16x32_bf16(fbb.f, whf.f, z, 0, 0, 0);
        D[3] = make_uint2(pk_rhu(d[0], d[1], sel), pk_rhu(d[2], d[3], sel));
        d = __builtin_amdgcn_mfma_f32_16x16x32_bf16(fab.f, whf.f, z, 0, 0, 0);
        D[4] = make_uint2(pk_rhu(d[0], d[1], sel), pk_rhu(d[2], d[3], sel));
    };

    float lsum = 0.f;

    // V-pass for one 16-row out-tile from D_prev (chunk t) + D_cur (chunk t+1).
    auto vstep = [&](const uint2* Dp, const uint2* Dc) {
        f32x4 res[5];
#pragma unroll
        for (int p = 0; p < 5; ++p) {
            frag Bf;
            unsigned t0, t1;
            t0 = __shfl(Dp[p].x, srcA, 64); t1 = __shfl(Dc[p].x, srcA, 64);
            Bf.u[0] = hi ? t1 : t0;
            t0 = __shfl(Dp[p].y, srcA, 64); t1 = __shfl(Dc[p].y, srcA, 64);
            Bf.u[1] = hi ? t1 : t0;
            t0 = __shfl(Dp[p].x, srcB, 64); t1 = __shfl(Dc[p].x, srcB, 64);
            Bf.u[2] = hi ? t1 : t0;
            t0 = __shfl(Dp[p].y, srcB, 64); t1 = __shfl(Dc[p].y, srcB, 64);
            Bf.u[3] = hi ? t1 : t0;
            res[p] = __builtin_amdgcn_mfma_f32_16x16x32_bf16(whf.f, Bf.f, z, 0, 0, 0);
        }
#pragma unroll
        for (int j = 0; j < 4; ++j) {
            const float mu1 = res[0][j];
            const float mu2 = res[1][j];
            const float m1s = mu1 * mu1;
            const float m2s = mu2 * mu2;
            const float m12 = mu1 * mu2;
            const float s11 = res[2][j] - m1s;
            const float s22 = res[3][j] - m2s;
            const float s12 = res[4][j] - m12;
            const float num = (2.f * m12 + C1c) * (2.f * s12 + C2c);
            const float den = (m1s + m2s + C1c) * (s11 + s22 + C2c);
            lsum = fmaf(num, __builtin_amdgcn_rcpf(den), lsum);
        }
    };

    // ---- Main march: BY/16+1 chunks -> BY/16 tiles, 2-deep prefetch, ping-pong ----
    float aE[8], bE[8], aO[8], bO[8];
    uint2 A0[5], A1[5];

    hload(0, aE, bE);
    hload(1, aO, bO);
    hproc(aE, bE, A0);                    // D of chunk 0

    for (int tt = 0; tt < NTT; ++tt) {    // tiles t = 2tt, 2tt+1
        hload(2 * tt + 2, aE, bE);        // chunk 2tt+2 (max BY/16)
        hproc(aO, bO, A1);                // D of chunk 2tt+1
        vstep(A0, A1);                    // tile 2tt
        if (tt < NTT - 1) hload(2 * tt + 3, aO, bO);   // chunk 2tt+3 (last skipped)
        hproc(aE, bE, A0);                // D of chunk 2tt+2
        vstep(A1, A0);                    // tile 2tt+1
    }

    // ---- Block reduction -> per-block partial ----
#pragma unroll
    for (int off = 32; off > 0; off >>= 1)
        lsum += __shfl_down(lsum, off, 64);

    __shared__ float wsum[4];
    if (lane == 0) wsum[wave] = lsum;
    __syncthreads();
    if (tid == 0) {
        float tot = wsum[0] + wsum[1] + wsum[2] + wsum[3];
        const int bid = (blockIdx.z * gridDim.y + blockIdx.y) * gridDim.x + blockIdx.x;
        partials[bid] = tot;
    }
}

__global__ __launch_bounds__(256)
void ssim_reduce_kernel(const float* __restrict__ partials,
                        float* __restrict__ out)
{
    __shared__ double sm[256];
    double s = 0.0;
    for (int i = threadIdx.x; i < NBLK; i += 256) s += (double)partials[i];
    sm[threadIdx.x] = s;
    __syncthreads();
    for (int stride = 128; stride > 0; stride >>= 1) {
        if (threadIdx.x < stride) sm[threadIdx.x] += sm[threadIdx.x + stride];
        __syncthreads();
    }
    if (threadIdx.x == 0) {
        double mean = sm[0] / (double)((size_t)NPL * IMW * IMH);
        out[0] = (float)(1.0 - mean);
    }
}

extern "C" void kernel_launch(void* const* d_in, const int* in_sizes, int n_in,
                              void* d_out, int out_size, void* d_ws, size_t ws_size,
                              hipStream_t stream)
{
    (void)in_sizes; (void)n_in; (void)out_size; (void)ws_size;
    const float* img1 = (const float*)d_in[0];
    const float* img2 = (const float*)d_in[1];
    float* out = (float*)d_out;

    unsigned int* wbuf = (unsigned int*)d_ws;              // 1 KB weight table
    float* partials = (float*)((char*)d_ws + 4096);        // NBLK floats

    ssim_weight_setup<<<1, 64, 0, stream>>>(wbuf);
    dim3 grid(GX, GYB, NPL);
    ssim_mfma<<<grid, 256, 0, stream>>>(img1, img2, wbuf, partials);
    ssim_reduce_kernel<<<1, 256, 0, stream>>>(partials, out);
}

// Round 2
// 47.941 us; speedup vs baseline: 1.1350x; 1.1350x over previous
//
#include <hip/hip_runtime.h>

// SSIM v14: v12 structure (BY=256, wave-autonomous MFMA conv) with the
// vstep shuffle block ELIMINATED. Round-1 showed doubling waves/CU does
// not help -> latency sits on the per-CU LDS pipe: 40 ds_bpermute + 20
// cndmask per tile (SQ_LDS_BANK_CONFLICT = 2/bpermute confirmed).
// Key identity: V-MFMA B-frag layout is k=lg*8+j, n=ln; H-pass D-frag is
// row=lg*4+j, col=ln. Choosing the V B-row permutation
//   k=lg*8+j  <->  window row (j<4 ? lg*4+j : 12+lg*4+j)
// makes the lane-local packed H outputs {Dp.x,Dp.y,Dc.x,Dc.y} the V
// B-fragment VERBATIM (zero cross-lane ops). The row permutation is
// absorbed into a second precomputed weight fragment whv with rows
// permuted the same way: whv[k][n] = wt[wr(k)-n-3]. Same 11 products
// per output pixel; only the MFMA's internal k-summation order changes
// (<=1 ulp f32; absmax stays at the bf16 plateau 0.0078125).

typedef __attribute__((ext_vector_type(8))) short bf16x8;
typedef __attribute__((ext_vector_type(4))) float f32x4;

constexpr int PAD  = 5;
constexpr int TX   = 64;             // block out-cols (4 waves x 16)
constexpr int BY   = 256;            // block out-rows
constexpr int IMW  = 512;
constexpr int IMH  = 512;
constexpr int NPL  = 48;
constexpr int GX   = IMW / TX;       // 8
constexpr int GYB  = IMH / BY;       // 2
constexpr int NBLK = GX * GYB * NPL; // 768
constexpr int NTT  = BY / 32;        // main-loop iterations (2 tiles each)
constexpr float C1c = 0.01f * 0.01f;
constexpr float C2c = 0.03f * 0.03f;

union frag {
    bf16x8 f;
    unsigned int u[4];
    uint4 q;
};

// RNE f32->bf16 pair pack (setup kernel only).
__device__ __forceinline__ unsigned int pk_bf16(float lo, float hi) {
    unsigned int a = __float_as_uint(lo);
    unsigned int b = __float_as_uint(hi);
    a += 0x7FFFu + ((a >> 16) & 1u);
    b += 0x7FFFu + ((b >> 16) & 1u);
    return (b & 0xFFFF0000u) | (a >> 16);
}

// Fast pack: round-half-up + byte-perm merge (3 VALU ops per pair).
__device__ __forceinline__ unsigned int pk_rhu(float lo, float hi, unsigned sel) {
    unsigned int a = __float_as_uint(lo) + 0x8000u;
    unsigned int b = __float_as_uint(hi) + 0x8000u;
    unsigned int r;
    asm("v_perm_b32 %0, %1, %2, %3" : "=v"(r) : "v"(b), "v"(a), "s"(sel));
    return r;
}

// Normalized 11-tap Gaussian (sigma=1.5); wt[d] for d in [0,11), else 0.
__device__ __forceinline__ float wsel(int d) {
    float w = 0.f;
    w = (d == 0 || d == 10) ? 0.00102838f : w;
    w = (d == 1 || d == 9)  ? 0.00759876f : w;
    w = (d == 2 || d == 8)  ? 0.03600077f : w;
    w = (d == 3 || d == 7)  ? 0.10936082f : w;
    w = (d == 4 || d == 6)  ? 0.21300553f : w;
    w = (d == 5)            ? 0.26601171f : w;
    return w;
}

// Per-lane weight fragments (8 words/lane):
//   words 0..3: whf  — H-pass B-frag,  W[k][n] = wt[k-n-3],   k = lg*8+j
//   words 4..7: whv  — V-pass A-frag with permuted rows,
//                      W'[k][n] = wt[wr(k)-n-3],
//                      wr(k) = (j<4 ? lg*4+j : 12+lg*4+j), j = k&7
__global__ void ssim_weight_setup(unsigned int* __restrict__ wbuf)
{
    const int lane = threadIdx.x & 63;
    const int ln   = lane & 15;
    const int lg   = lane >> 4;
#pragma unroll
    for (int w = 0; w < 4; ++w) {
        const int ka = lg * 8 + 2 * w;
        wbuf[lane * 8 + w] = pk_bf16(wsel(ka - ln - 3), wsel(ka + 1 - ln - 3));
        // permuted V rows: j = 2w, 2w+1 stay within the same half (j<4 vs j>=4)
        const int j0  = 2 * w;
        const int wr0 = (j0 < 4) ? (lg * 4 + j0) : (12 + lg * 4 + j0);
        wbuf[lane * 8 + 4 + w] = pk_bf16(wsel(wr0 - ln - 3), wsel(wr0 + 1 - ln - 3));
    }
}

__global__ __launch_bounds__(256, 4)
void ssim_mfma(const float* __restrict__ img1, const float* __restrict__ img2,
               const unsigned int* __restrict__ wbuf,
               float* __restrict__ partials)
{
    const int tid  = threadIdx.x;
    const int lane = tid & 63;
    const int wave = tid >> 6;        // 0..3
    const int ln   = lane & 15;
    const int lg   = lane >> 4;       // 0..3
    const int tx0w = blockIdx.x * TX + wave * 16;   // wave's 16 out-cols
    const int y0   = blockIdx.y * BY;
    const float* __restrict__ p1 = img1 + (size_t)blockIdx.z * (IMW * IMH);
    const float* __restrict__ p2 = img2 + (size_t)blockIdx.z * (IMW * IMH);
    const unsigned int sel = 0x07060302u;

    frag whf, whv;
    whf.q = reinterpret_cast<const uint4*>(wbuf)[lane * 2];
    whv.q = reinterpret_cast<const uint4*>(wbuf)[lane * 2 + 1];

    const f32x4 z = {0.f, 0.f, 0.f, 0.f};
    const int cbase = tx0w - 8 + lg * 8;            // lane's first img col

    // Load chunk c: 16 h-rows (img rows y0+16c-8 .. +7), 32 cols window.
    auto hload = [&](int c, float* a, float* b) {
        const int irow = y0 + 16 * c - 8 + ln;
        const bool rowok = (unsigned)irow < (unsigned)IMH;
#pragma unroll
        for (int h = 0; h < 2; ++h) {
            const int c4 = cbase + 4 * h;
            float4 va = make_float4(0.f, 0.f, 0.f, 0.f);
            float4 vb = make_float4(0.f, 0.f, 0.f, 0.f);
            if (rowok && ((unsigned)c4 <= (unsigned)(IMW - 4))) {
                va = *reinterpret_cast<const float4*>(p1 + (size_t)irow * IMW + c4);
                vb = *reinterpret_cast<const float4*>(p2 + (size_t)irow * IMW + c4);
            }
            a[4*h+0] = va.x; a[4*h+1] = va.y; a[4*h+2] = va.z; a[4*h+3] = va.w;
            b[4*h+0] = vb.x; b[4*h+1] = vb.y; b[4*h+2] = vb.z; b[4*h+3] = vb.w;
        }
    };

    // H-pass for one chunk: 5 MFMAs -> packed D (uint2 per plane).
    // D word .x = rows lg*4+{0,1}, .y = rows lg*4+{2,3} (col = ln).
    auto hproc = [&](const float* a, const float* b, uint2* D) {
        frag fa, fb, faa, fbb, fab;
#pragma unroll
        for (int w = 0; w < 4; ++w) {
            const float a0 = a[2*w], a1 = a[2*w+1];
            const float b0 = b[2*w], b1 = b[2*w+1];
            fa.u[w]  = pk_rhu(a0,      a1,      sel);
            fb.u[w]  = pk_rhu(b0,      b1,      sel);
            faa.u[w] = pk_rhu(a0 * a0, a1 * a1, sel);
            fbb.u[w] = pk_rhu(b0 * b0, b1 * b1, sel);
            fab.u[w] = pk_rhu(a0 * b0, a1 * b1, sel);
        }
        f32x4 d;
        d = __builtin_amdgcn_mfma_f32_16x16x32_bf16(fa.f,  whf.f, z, 0, 0, 0);
        D[0] = make_uint2(pk_rhu(d[0], d[1], sel), pk_rhu(d[2], d[3], sel));
        d = __builtin_amdgcn_mfma_f32_16x16x32_bf16(fb.f,  whf.f, z, 0, 0, 0);
        D[1] = make_uint2(pk_rhu(d[0], d[1], sel), pk_rhu(d[2], d[3], sel));
        d = __builtin_amdgcn_mfma_f32_16x16x32_bf16(faa.f, whf.f, z, 0, 0, 0);
        D[2] = make_uint2(pk_rhu(d[0], d[1], sel), pk_rhu(d[2], d[3], sel));
        d = __builtin_amdgcn_mfma_f32_16x16x32_bf16(fbb.f, whf.f, z, 0, 0, 0);
        D[3] = make_uint2(pk_rhu(d[0], d[1], sel), pk_rhu(d[2], d[3], sel));
        d = __builtin_amdgcn_mfma_f32_16x16x32_bf16(fab.f, whf.f, z, 0, 0, 0);
        D[4] = make_uint2(pk_rhu(d[0], d[1], sel), pk_rhu(d[2], d[3], sel));
    };

    float lsum = 0.f;

    // V-pass for one 16-row out-tile from D_prev (chunk t) + D_cur (chunk t+1).
    // Zero shuffles: lane-local {Dp.x,Dp.y,Dc.x,Dc.y} IS the B-frag under the
    // whv row permutation (B row lg*8+j <-> window row (j<4?lg*4+j:12+lg*4+j)).
    auto vstep = [&](const uint2* Dp, const uint2* Dc) {
        f32x4 res[5];
#pragma unroll
        for (int p = 0; p < 5; ++p) {
            frag Bf;
            Bf.u[0] = Dp[p].x; Bf.u[1] = Dp[p].y;
            Bf.u[2] = Dc[p].x; Bf.u[3] = Dc[p].y;
            res[p] = __builtin_amdgcn_mfma_f32_16x16x32_bf16(whv.f, Bf.f, z, 0, 0, 0);
        }
#pragma unroll
        for (int j = 0; j < 4; ++j) {
            const float mu1 = res[0][j];
            const float mu2 = res[1][j];
            const float m1s = mu1 * mu1;
            const float m2s = mu2 * mu2;
            const float m12 = mu1 * mu2;
            const float s11 = res[2][j] - m1s;
            const float s22 = res[3][j] - m2s;
            const float s12 = res[4][j] - m12;
            const float num = (2.f * m12 + C1c) * (2.f * s12 + C2c);
            const float den = (m1s + m2s + C1c) * (s11 + s22 + C2c);
            lsum = fmaf(num, __builtin_amdgcn_rcpf(den), lsum);
        }
    };

    // ---- Main march: NTT*2+1 chunks -> NTT*2 tiles, 2-deep prefetch ----
    float aE[8], bE[8], aO[8], bO[8];
    uint2 A0[5], A1[5];

    hload(0, aE, bE);
    hload(1, aO, bO);
    hproc(aE, bE, A0);                    // D of chunk 0

    for (int tt = 0; tt < NTT; ++tt) {    // tiles t = 2tt, 2tt+1
        hload(2 * tt + 2, aE, bE);        // chunk 2tt+2
        hproc(aO, bO, A1);                // D of chunk 2tt+1
        vstep(A0, A1);                    // tile 2tt
        if (tt < NTT - 1) hload(2 * tt + 3, aO, bO);   // chunk 2tt+3 (last skipped)
        hproc(aE, bE, A0);                // D of chunk 2tt+2
        vstep(A1, A0);                    // tile 2tt+1
    }

    // ---- Block reduction -> per-block partial ----
#pragma unroll
    for (int off = 32; off > 0; off >>= 1)
        lsum += __shfl_down(lsum, off, 64);

    __shared__ float wsum[4];
    if (lane == 0) wsum[wave] = lsum;
    __syncthreads();
    if (tid == 0) {
        float tot = wsum[0] + wsum[1] + wsum[2] + wsum[3];
        const int bid = (blockIdx.z * gridDim.y + blockIdx.y) * gridDim.x + blockIdx.x;
        partials[bid] = tot;
    }
}

__global__ __launch_bounds__(256)
void ssim_reduce_kernel(const float* __restrict__ partials,
                        float* __restrict__ out)
{
    __shared__ double sm[256];
    double s = 0.0;
    for (int i = threadIdx.x; i < NBLK; i += 256) s += (double)partials[i];
    sm[threadIdx.x] = s;
    __syncthreads();
    for (int stride = 128; stride > 0; stride >>= 1) {
        if (threadIdx.x < stride) sm[threadIdx.x] += sm[threadIdx.x + stride];
        __syncthreads();
    }
    if (threadIdx.x == 0) {
        double mean = sm[0] / (double)((size_t)NPL * IMW * IMH);
        out[0] = (float)(1.0 - mean);
    }
}

extern "C" void kernel_launch(void* const* d_in, const int* in_sizes, int n_in,
                              void* d_out, int out_size, void* d_ws, size_t ws_size,
                              hipStream_t stream)
{
    (void)in_sizes; (void)n_in; (void)out_size; (void)ws_size;
    const float* img1 = (const float*)d_in[0];
    const float* img2 = (const float*)d_in[1];
    float* out = (float*)d_out;

    unsigned int* wbuf = (unsigned int*)d_ws;              // 2 KB weight table
    float* partials = (float*)((char*)d_ws + 4096);        // NBLK floats

    ssim_weight_setup<<<1, 64, 0, stream>>>(wbuf);
    dim3 grid(GX, GYB, NPL);
    ssim_mfma<<<grid, 256, 0, stream>>>(img1, img2, wbuf, partials);
    ssim_reduce_kernel<<<1, 256, 0, stream>>>(partials, out);
}